// Round 1
// baseline (128.795 us; speedup 1.0000x reference)
//
#include <hip/hip_runtime.h>

// B=32, C=8, L=2048, K=512, S=64, W=1985
// out[b,0,q] = max(0, max_w sum_c dot(xw_n[b,c,w,:], sn_n[c,q,:]) / 8)
//
// v2: operand-swapped MFMA. A = shapelets (rows = q, from LDS), B = windows
// (cols = w, from precomputed f16 x). In the 32x32 C/D layout col = lane&31,
// so the per-(c,w) inv-norm is a per-lane SCALAR folded into the B-frag with
// v_pk_mul_f16. No f32->f16 conversion and no per-row scaling in the main
// loop; regs drop to ~100 -> 4 waves/SIMD (vs 2).

#define B_ 32
#define C_ 8
#define L_ 2048
#define K_ 512
#define S_ 64
#define W_ 1985
#define XS_ 2176                      // padded f16 row stride (L_ + 128, 16B-mult)

typedef _Float16 f16x8  __attribute__((ext_vector_type(8)));
typedef _Float16 f16x8u __attribute__((ext_vector_type(8), aligned(4)));
typedef float    f32x16 __attribute__((ext_vector_type(16)));

// ---- prologue ----
// blocks 0..127: pack shapelets in MFMA frag layout (unchanged; the layout
//   serves as the A-operand now: lane&31 -> q-row, (lane>>5)*8+j -> k).
// blocks 128..383: per (b,c) row: window inv-norms (with /8 folded in),
//   plus TWO f16 copies of x (xh1 shifted by one element) so that every
//   lane's window-offset f16x8 load is 4-byte aligned. Pad = 0. Zero out.
__global__ __launch_bounds__(256)
void prep_k(const float* __restrict__ x, const float* __restrict__ sh,
            _Float16* __restrict__ Bp, float* __restrict__ invn,
            _Float16* __restrict__ xh0, _Float16* __restrict__ xh1,
            float* __restrict__ out) {
    __shared__ float xr[L_];
    const int tid = threadIdx.x;
    const int blk = blockIdx.x;

    if (blk < 128) {
        const int sb   = blk * 4 + (tid >> 6);   // 0..511 = c(8) x kq(4) x nt(16)
        const int c    = sb >> 6;
        const int kq   = (sb >> 4) & 3;
        const int nt   = sb & 15;
        const int lane = tid & 63;
        const int half = lane >> 5;
        const int q    = nt * 32 + (lane & 31);

        const float4* sp = (const float4*)(sh + (size_t)(c * K_ + q) * S_);
        float ss = 0.f;
        #pragma unroll
        for (int i = 0; i < 8; ++i) {
            float4 v = sp[half * 8 + i];
            ss += v.x * v.x + v.y * v.y + v.z * v.z + v.w * v.w;
        }
        ss += __shfl_xor(ss, 32);
        float inv = 1.f / fmaxf(sqrtf(ss), 1e-8f);

        float4 u0 = sp[kq * 4 + half * 2];
        float4 u1 = sp[kq * 4 + half * 2 + 1];
        f16x8 o;
        o[0] = (_Float16)(u0.x * inv); o[1] = (_Float16)(u0.y * inv);
        o[2] = (_Float16)(u0.z * inv); o[3] = (_Float16)(u0.w * inv);
        o[4] = (_Float16)(u1.x * inv); o[5] = (_Float16)(u1.y * inv);
        o[6] = (_Float16)(u1.z * inv); o[7] = (_Float16)(u1.w * inv);
        ((f16x8*)Bp)[((c * 4 + kq) * 16 + nt) * 64 + lane] = o;
    } else {
        const int r = blk - 128;                 // 0..255 = b*8+c
        const float* xp = x + (size_t)r * L_;
        for (int i = tid; i < L_ / 4; i += 256)
            ((float4*)xr)[i] = ((const float4*)xp)[i];
        __syncthreads();

        float* ivp = invn + (size_t)r * L_;
        const int w0 = tid * 8;
        float ss = 0.f;
        if (w0 < W_) {
            #pragma unroll
            for (int j = 0; j < S_; ++j) { float v = xr[w0 + j]; ss += v * v; }
        }
        #pragma unroll
        for (int u = 0; u < 8; ++u) {
            int w = w0 + u;
            float o = 0.f;
            if (u > 0 && w < W_)
                ss += xr[w + 63] * xr[w + 63] - xr[w - 1] * xr[w - 1];
            if (w < W_) o = 0.125f / fmaxf(sqrtf(ss), 1e-8f);
            if (w < L_) ivp[w] = o;
        }

        // f16 copies: xh0[i] = x[i], xh1[i] = x[i+1]; zero-fill pad region.
        _Float16* p0 = xh0 + (size_t)r * XS_;
        _Float16* p1 = xh1 + (size_t)r * XS_;
        for (int i = tid; i < XS_ / 8; i += 256) {
            f16x8 o0, o1;
            #pragma unroll
            for (int j = 0; j < 8; ++j) {
                int e = i * 8 + j;
                o0[j] = (_Float16)((e     < L_) ? xr[e]     : 0.f);
                o1[j] = (_Float16)((e + 1 < L_) ? xr[e + 1] : 0.f);
            }
            ((f16x8*)p0)[i] = o0;
            ((f16x8*)p1)[i] = o1;
        }
        if (r < 64) out[r * 256 + tid] = 0.f;    // zero output
    }
}

// ---- main: swapped-operand MFMA, barrier-free K-loop ----
// grid (2 cw, 16 qg, 32 b) = 1024 blocks = exactly 4 blocks/CU.
// Block: 4 waves; wave owns 32 q-rows (qg) x 256 windows (8 tiles of 32).
// A-frags (shapelets) staged once into 32 KB LDS, read lane-contiguous
// (conflict-free ds_read_b128). B-frags: 8 consecutive f16 per lane from
// xh0/xh1 (parity-selected base keeps dwordx4 4B-aligned), scaled by the
// per-lane window inv-norm via v_pk_mul_f16, folded pre-MFMA (linear in B).
// acc accumulates over c and k; relu+max over w = per-lane fmax over tiles
// then one 5-step shfl_xor reduce per wave.
__global__ __launch_bounds__(256, 4)
void mcs_k(const _Float16* __restrict__ xh0, const _Float16* __restrict__ xh1,
           const _Float16* __restrict__ Bp, const float* __restrict__ invn,
           float* __restrict__ out) {
    const int cw  = blockIdx.x;           // 0..1   window half
    const int qg  = blockIdx.y;           // 0..15  32-row shapelet group
    const int b   = blockIdx.z;           // 0..31
    const int tid = threadIdx.x;
    const int lane = tid & 63;
    const int wv   = tid >> 6;
    const int l31  = lane & 31;
    const int lh   = lane >> 5;

    // stage this qg's A-frags: 32 frags (c*4+ks) x 64 lanes x 16B = 32 KB
    __shared__ f16x8 As[2048];
    {
        const f16x8* bp = (const f16x8*)Bp;
        #pragma unroll
        for (int k = 0; k < 8; ++k) {
            int e = k * 256 + tid;
            As[e] = bp[((e >> 6) * 16 + qg) * 64 + (e & 63)];
        }
    }
    __syncthreads();

    // parity-selected x base: odd window columns read the shifted copy so the
    // element offset (w + k) - parity stays even -> 4B-aligned dwordx4.
    const _Float16* xb = (l31 & 1) ? (xh1 - 1) : xh0;
    const int wbase = cw * 1024 + wv * 256;

    f32x16 mx;
    #pragma unroll
    for (int r = 0; r < 16; ++r) mx[r] = 0.f;

    #pragma unroll 1
    for (int t = 0; t < 8; ++t) {
        const int w0 = wbase + t * 32;    // this tile's window base (col = l31)
        f32x16 acc;
        #pragma unroll
        for (int r = 0; r < 16; ++r) acc[r] = 0.f;

        #pragma unroll 2
        for (int c = 0; c < C_; ++c) {
            const int row = b * C_ + c;
            const float iv = invn[(size_t)row * L_ + w0 + l31];  // 0 for w>=W_
            const _Float16 ivh = (_Float16)iv;
            f16x8 ivs;
            #pragma unroll
            for (int j = 0; j < 8; ++j) ivs[j] = ivh;

            const _Float16* xp = xb + (size_t)row * XS_ + w0 + l31 + lh * 8;
            f16x8 bf[4], af[4];
            #pragma unroll
            for (int ks = 0; ks < 4; ++ks)
                bf[ks] = *(const f16x8u*)(xp + ks * 16);
            #pragma unroll
            for (int ks = 0; ks < 4; ++ks)
                af[ks] = As[(c * 4 + ks) * 64 + lane];
            #pragma unroll
            for (int ks = 0; ks < 4; ++ks) {
                f16x8 bs = bf[ks] * ivs;                  // 4x v_pk_mul_f16
                acc = __builtin_amdgcn_mfma_f32_32x32x16_f16(
                          af[ks], bs, acc, 0, 0, 0);
            }
        }
        #pragma unroll
        for (int r = 0; r < 16; ++r) mx[r] = fmaxf(mx[r], acc[r]);  // relu via init 0
    }

    // max over the 32 window-columns (lanes) within each half-wave
    #pragma unroll
    for (int s = 16; s >= 1; s >>= 1)
        #pragma unroll
        for (int r = 0; r < 16; ++r)
            mx[r] = fmaxf(mx[r], __shfl_xor(mx[r], s));

    if (l31 == 0) {
        #pragma unroll
        for (int r = 0; r < 16; ++r) {
            const int q = qg * 32 + (r & 3) + 8 * (r >> 2) + 4 * lh;
            atomicMax((unsigned int*)(out + (size_t)b * K_ + q),
                      __float_as_uint(mx[r]));   // values >= 0, uint-max valid
        }
    }
}

extern "C" void kernel_launch(void* const* d_in, const int* in_sizes, int n_in,
                              void* d_out, int out_size, void* d_ws, size_t ws_size,
                              hipStream_t stream) {
    const float* x  = (const float*)d_in[0];   // (32, 8, 2048) fp32
    const float* sh = (const float*)d_in[1];   // (8, 512, 64) fp32
    float* out = (float*)d_out;                // (32, 1, 512) fp32

    // workspace: Bp 512KB | invn 2MB | xh0 1.06MB | xh1 1.06MB  (~4.7MB)
    _Float16* Bp   = (_Float16*)d_ws;
    float*    invn = (float*)((char*)d_ws + (512 << 10));
    _Float16* xh0  = (_Float16*)((char*)d_ws + (512 << 10) + (2 << 20));
    _Float16* xh1  = xh0 + (size_t)B_ * C_ * XS_;

    prep_k<<<dim3(384), dim3(256), 0, stream>>>(x, sh, Bp, invn, xh0, xh1, out);
    mcs_k<<<dim3(2, 16, B_), dim3(256), 0, stream>>>(xh0, xh1, Bp, invn, out);
}

// Round 2
// 125.733 us; speedup vs baseline: 1.0243x; 1.0243x over previous
//
#include <hip/hip_runtime.h>

// B=32, C=8, L=2048, K=512, S=64, W=1985
// out[b,0,q] = max(0, max_w sum_c dot(xw_n[b,c,w,:], sn_n[c,q,:]) / 8)
//
// v3: v1's register-tile structure (2 window-tiles x 4 shapelet-tiles per
// wave, 8 independent acc chains, no LDS, barrier-free) with A-fragments
// built from PRECOMPUTED f16 x (dual one-element-shifted copies keep every
// lane's f16x8 load 4B-aligned). Per-window inv-norm folds in as
// v_pk_mul_f16 -- the f32 mul+cvt storm that capped v1 at 29.5% MfmaUtil
// is gone. v2's LDS-per-MFMA feed (4x over LDS BW) is also gone.

#define B_ 32
#define C_ 8
#define L_ 2048
#define K_ 512
#define S_ 64
#define W_ 1985
#define XS_ 2176                      // padded f16 row stride (L_ + 128)

typedef _Float16 f16x8  __attribute__((ext_vector_type(8)));
typedef _Float16 f16x8u __attribute__((ext_vector_type(8), aligned(4)));
typedef float    f32x16 __attribute__((ext_vector_type(16)));

// ---- prologue ----
// blocks 0..127: pack shapelets in 32x32x16 frag layout:
//   Bp unit ((c*4+kq)*16 + nt)*64 + lane, value[j] =
//   sn_norm[c][nt*32 + (lane&31)][kq*16 + (lane>>5)*8 + j]
// blocks 128..383: per (b,c) row: window inv-norms (/8 folded), f16 copies
//   xh0[i]=x[i], xh1[i]=x[i+1] (zero-padded to XS_), zero out.
__global__ __launch_bounds__(256)
void prep_k(const float* __restrict__ x, const float* __restrict__ sh,
            _Float16* __restrict__ Bp, float* __restrict__ invn,
            _Float16* __restrict__ xh0, _Float16* __restrict__ xh1,
            float* __restrict__ out) {
    __shared__ float xr[L_];
    const int tid = threadIdx.x;
    const int blk = blockIdx.x;

    if (blk < 128) {
        const int sb   = blk * 4 + (tid >> 6);   // 0..511 = c(8) x kq(4) x nt(16)
        const int c    = sb >> 6;
        const int kq   = (sb >> 4) & 3;
        const int nt   = sb & 15;
        const int lane = tid & 63;
        const int half = lane >> 5;
        const int q    = nt * 32 + (lane & 31);

        const float4* sp = (const float4*)(sh + (size_t)(c * K_ + q) * S_);
        float ss = 0.f;
        #pragma unroll
        for (int i = 0; i < 8; ++i) {
            float4 v = sp[half * 8 + i];
            ss += v.x * v.x + v.y * v.y + v.z * v.z + v.w * v.w;
        }
        ss += __shfl_xor(ss, 32);
        float inv = 1.f / fmaxf(sqrtf(ss), 1e-8f);

        float4 u0 = sp[kq * 4 + half * 2];
        float4 u1 = sp[kq * 4 + half * 2 + 1];
        f16x8 o;
        o[0] = (_Float16)(u0.x * inv); o[1] = (_Float16)(u0.y * inv);
        o[2] = (_Float16)(u0.z * inv); o[3] = (_Float16)(u0.w * inv);
        o[4] = (_Float16)(u1.x * inv); o[5] = (_Float16)(u1.y * inv);
        o[6] = (_Float16)(u1.z * inv); o[7] = (_Float16)(u1.w * inv);
        ((f16x8*)Bp)[((c * 4 + kq) * 16 + nt) * 64 + lane] = o;
    } else {
        const int r = blk - 128;                 // 0..255 = b*8+c
        const float* xp = x + (size_t)r * L_;
        for (int i = tid; i < L_ / 4; i += 256)
            ((float4*)xr)[i] = ((const float4*)xp)[i];
        __syncthreads();

        float* ivp = invn + (size_t)r * L_;
        const int w0 = tid * 8;
        float ss = 0.f;
        if (w0 < W_) {
            #pragma unroll
            for (int j = 0; j < S_; ++j) { float v = xr[w0 + j]; ss += v * v; }
        }
        #pragma unroll
        for (int u = 0; u < 8; ++u) {
            int w = w0 + u;
            float o = 0.f;
            if (u > 0 && w < W_)
                ss += xr[w + 63] * xr[w + 63] - xr[w - 1] * xr[w - 1];
            if (w < W_) o = 0.125f / fmaxf(sqrtf(ss), 1e-8f);
            if (w < L_) ivp[w] = o;
        }

        _Float16* p0 = xh0 + (size_t)r * XS_;
        _Float16* p1 = xh1 + (size_t)r * XS_;
        for (int i = tid; i < XS_ / 8; i += 256) {
            f16x8 o0, o1;
            #pragma unroll
            for (int j = 0; j < 8; ++j) {
                int e = i * 8 + j;
                o0[j] = (_Float16)((e     < L_) ? xr[e]     : 0.f);
                o1[j] = (_Float16)((e + 1 < L_) ? xr[e + 1] : 0.f);
            }
            ((f16x8*)p0)[i] = o0;
            ((f16x8*)p1)[i] = o1;
        }
        if (r < 64) out[r * 256 + tid] = 0.f;    // zero output
    }
}

// ---- main: barrier-free per-wave MFMA GEMM + relu + max ----
// grid (16 wt, 2 ng, 32 b) = 1024 blocks, 4 waves (mg = window subgroup,
// nw = column quarter). Wave: 64 windows (2 x 32 rows) x 128 cols (4 x 32).
// A (rows = windows): f16x8 straight from xh0/xh1, parity-selected base so
// the per-lane element offset stays 4B-aligned; scaled by per-lane f16
// inv-norm via v_pk_mul_f16 (4/frag). B (cols = shapelets): 16 dwordx4 per
// c from L2-resident packed Bp. 8 independent acc chains; no LDS, no syncs.
__global__ __launch_bounds__(256, 2)
void mcs_k(const _Float16* __restrict__ xh0, const _Float16* __restrict__ xh1,
           const _Float16* __restrict__ Bp, const float* __restrict__ invn,
           float* __restrict__ out) {
    const int wt  = blockIdx.x;
    const int ng  = blockIdx.y;
    const int b   = blockIdx.z;
    const int tid = threadIdx.x;
    const int lane = tid & 63;
    const int wv   = tid >> 6;
    const int mg   = wv >> 1;
    const int nw   = wv & 1;

    const int l31 = lane & 31;
    const int lh  = lane >> 5;
    const int Wb  = wt * 128 + mg * 64;   // wave's window base
    const int m0  = Wb + l31;             // lane's two window rows
    const int m1  = Wb + 32 + l31;

    // parity-selected x base keeps every f16x8 load 4B-aligned
    const _Float16* xb = (l31 & 1) ? (xh1 - 1) : xh0;

    f32x16 acc[2][4];
    #pragma unroll
    for (int mt = 0; mt < 2; ++mt)
        #pragma unroll
        for (int nt = 0; nt < 4; ++nt)
            #pragma unroll
            for (int r = 0; r < 16; ++r) acc[mt][nt][r] = 0.f;

    #pragma unroll 1
    for (int c = 0; c < C_; ++c) {
        const int row = b * C_ + c;
        const float iv0 = invn[(size_t)row * L_ + m0];  // 0 for invalid windows
        const float iv1 = invn[(size_t)row * L_ + m1];
        const _Float16 h0 = (_Float16)iv0, h1 = (_Float16)iv1;
        f16x8 is0, is1;
        #pragma unroll
        for (int j = 0; j < 8; ++j) { is0[j] = h0; is1[j] = h1; }

        // B fragments: 16 x dwordx4 from packed L2-resident Bp
        const f16x8* bbase = (const f16x8*)Bp +
            ((c * 4) * 16 + ng * 8 + nw * 4) * 64 + lane;
        f16x8 bfr[4][4];
        #pragma unroll
        for (int ks = 0; ks < 4; ++ks)
            #pragma unroll
            for (int nt = 0; nt < 4; ++nt)
                bfr[ks][nt] = bbase[(ks * 16 + nt) * 64];

        // A fragments: f16x8 load + 4x v_pk_mul_f16 scale, no cvt
        const _Float16* xp = xb + (size_t)row * XS_ + Wb + l31 + lh * 8;
        f16x8 af[2][4];
        #pragma unroll
        for (int mt = 0; mt < 2; ++mt)
            #pragma unroll
            for (int ks = 0; ks < 4; ++ks) {
                f16x8 v = *(const f16x8u*)(xp + mt * 32 + ks * 16);
                af[mt][ks] = v * (mt ? is1 : is0);
            }

        #pragma unroll
        for (int ks = 0; ks < 4; ++ks)
            #pragma unroll
            for (int nt = 0; nt < 4; ++nt)
                #pragma unroll
                for (int mt = 0; mt < 2; ++mt)
                    acc[mt][nt] = __builtin_amdgcn_mfma_f32_32x32x16_f16(
                        af[mt][ks], bfr[ks][nt], acc[mt][nt], 0, 0, 0);
    }

    // epilogue: relu + max over windows (invalid windows exactly 0).
    // 32x32 C/D: col = lane&31; lane and lane^32 cover the same col.
    #pragma unroll
    for (int nt = 0; nt < 4; ++nt) {
        float m = 0.f;
        #pragma unroll
        for (int mt = 0; mt < 2; ++mt)
            #pragma unroll
            for (int r = 0; r < 16; ++r)
                m = fmaxf(m, acc[mt][nt][r]);
        m = fmaxf(m, __shfl_xor(m, 32));
        if (lane < 32)
            atomicMax((unsigned int*)(out + b * K_ + ng * 256 + nw * 128 + nt * 32 + l31),
                      __float_as_uint(m));   // values >= 0, uint-max valid
    }
}

extern "C" void kernel_launch(void* const* d_in, const int* in_sizes, int n_in,
                              void* d_out, int out_size, void* d_ws, size_t ws_size,
                              hipStream_t stream) {
    const float* x  = (const float*)d_in[0];   // (32, 8, 2048) fp32
    const float* sh = (const float*)d_in[1];   // (8, 512, 64) fp32
    float* out = (float*)d_out;                // (32, 1, 512) fp32

    // workspace: Bp 512KB | invn 2MB | xh0 ~1.06MB | xh1 ~1.06MB
    _Float16* Bp   = (_Float16*)d_ws;
    float*    invn = (float*)((char*)d_ws + (512 << 10));
    _Float16* xh0  = (_Float16*)((char*)d_ws + (512 << 10) + (2 << 20));
    _Float16* xh1  = xh0 + (size_t)B_ * C_ * XS_;

    prep_k<<<dim3(384), dim3(256), 0, stream>>>(x, sh, Bp, invn, xh0, xh1, out);
    mcs_k<<<dim3(16, 2, B_), dim3(256), 0, stream>>>(xh0, xh1, Bp, invn, out);
}

// Round 3
// 103.999 us; speedup vs baseline: 1.2384x; 1.2090x over previous
//
#include <hip/hip_runtime.h>

// B=32, C=8, L=2048, K=512, S=64, W=1985
// out[b,0,q] = max(0, max_w sum_c dot(xw_n[b,c,w,:], sn_n[c,q,:]) / 8)
//
// v4: software-pipelined c-loop. v3 showed both pipes idle (MfmaUtil 18.7%,
// VALU 7.9%, HBM 1.2%): every c-iteration exposed a full load->waitcnt->MFMA
// round trip and the 2 in-phase waves/SIMD stalled together. v4 prefetches
// iteration c+1's fragments (registers, double-buffered, NAMED buffers) before
// iteration c's MFMA block, so the ~200-600cy L2 latency hides under 512cy of
// MFMA issue. Wave tile shrunk to 64 windows x 64 q (acc 64 AGPR) to afford
// the double buffers at 2 waves/SIMD.

#define B_ 32
#define C_ 8
#define L_ 2048
#define K_ 512
#define S_ 64
#define W_ 1985
#define XS_ 2176                      // padded f16 row stride (L_ + 128)

typedef _Float16 f16x8  __attribute__((ext_vector_type(8)));
typedef _Float16 f16x8u __attribute__((ext_vector_type(8), aligned(4)));
typedef float    f32x16 __attribute__((ext_vector_type(16)));

// ---- prologue (unchanged from v3, harness-verified) ----
// blocks 0..127: pack shapelets in 32x32x16 frag layout:
//   Bp unit ((c*4+kq)*16 + ntg)*64 + lane, value[j] =
//   sn_norm[c][ntg*32 + (lane&31)][kq*16 + (lane>>5)*8 + j]
// blocks 128..383: per (b,c) row: window inv-norms (/8 folded), f16 copies
//   xh0[i]=x[i], xh1[i]=x[i+1] (zero-padded to XS_), zero out.
__global__ __launch_bounds__(256)
void prep_k(const float* __restrict__ x, const float* __restrict__ sh,
            _Float16* __restrict__ Bp, float* __restrict__ invn,
            _Float16* __restrict__ xh0, _Float16* __restrict__ xh1,
            float* __restrict__ out) {
    __shared__ float xr[L_];
    const int tid = threadIdx.x;
    const int blk = blockIdx.x;

    if (blk < 128) {
        const int sb   = blk * 4 + (tid >> 6);   // 0..511 = c(8) x kq(4) x ntg(16)
        const int c    = sb >> 6;
        const int kq   = (sb >> 4) & 3;
        const int nt   = sb & 15;
        const int lane = tid & 63;
        const int half = lane >> 5;
        const int q    = nt * 32 + (lane & 31);

        const float4* sp = (const float4*)(sh + (size_t)(c * K_ + q) * S_);
        float ss = 0.f;
        #pragma unroll
        for (int i = 0; i < 8; ++i) {
            float4 v = sp[half * 8 + i];
            ss += v.x * v.x + v.y * v.y + v.z * v.z + v.w * v.w;
        }
        ss += __shfl_xor(ss, 32);
        float inv = 1.f / fmaxf(sqrtf(ss), 1e-8f);

        float4 u0 = sp[kq * 4 + half * 2];
        float4 u1 = sp[kq * 4 + half * 2 + 1];
        f16x8 o;
        o[0] = (_Float16)(u0.x * inv); o[1] = (_Float16)(u0.y * inv);
        o[2] = (_Float16)(u0.z * inv); o[3] = (_Float16)(u0.w * inv);
        o[4] = (_Float16)(u1.x * inv); o[5] = (_Float16)(u1.y * inv);
        o[6] = (_Float16)(u1.z * inv); o[7] = (_Float16)(u1.w * inv);
        ((f16x8*)Bp)[((c * 4 + kq) * 16 + nt) * 64 + lane] = o;
    } else {
        const int r = blk - 128;                 // 0..255 = b*8+c
        const float* xp = x + (size_t)r * L_;
        for (int i = tid; i < L_ / 4; i += 256)
            ((float4*)xr)[i] = ((const float4*)xp)[i];
        __syncthreads();

        float* ivp = invn + (size_t)r * L_;
        const int w0 = tid * 8;
        float ss = 0.f;
        if (w0 < W_) {
            #pragma unroll
            for (int j = 0; j < S_; ++j) { float v = xr[w0 + j]; ss += v * v; }
        }
        #pragma unroll
        for (int u = 0; u < 8; ++u) {
            int w = w0 + u;
            float o = 0.f;
            if (u > 0 && w < W_)
                ss += xr[w + 63] * xr[w + 63] - xr[w - 1] * xr[w - 1];
            if (w < W_) o = 0.125f / fmaxf(sqrtf(ss), 1e-8f);
            if (w < L_) ivp[w] = o;
        }

        _Float16* p0 = xh0 + (size_t)r * XS_;
        _Float16* p1 = xh1 + (size_t)r * XS_;
        for (int i = tid; i < XS_ / 8; i += 256) {
            f16x8 o0, o1;
            #pragma unroll
            for (int j = 0; j < 8; ++j) {
                int e = i * 8 + j;
                o0[j] = (_Float16)((e     < L_) ? xr[e]     : 0.f);
                o1[j] = (_Float16)((e + 1 < L_) ? xr[e + 1] : 0.f);
            }
            ((f16x8*)p0)[i] = o0;
            ((f16x8*)p1)[i] = o1;
        }
        if (r < 64) out[r * 256 + tid] = 0.f;    // zero output
    }
}

// fragment loads for channel c (runtime c, STATIC register buffers)
__device__ __forceinline__ void load_c(
    int c, const f16x8* __restrict__ bpbase, const _Float16* __restrict__ xbase,
    const float* __restrict__ ivbase, int m0, int m1,
    f16x8 (&bf)[8], f16x8 (&ar)[8], float (&iv)[2])
{
    iv[0] = ivbase[(size_t)c * L_ + m0];         // 0 for invalid windows
    iv[1] = ivbase[(size_t)c * L_ + m1];
    #pragma unroll
    for (int ks = 0; ks < 4; ++ks)
        #pragma unroll
        for (int nt = 0; nt < 2; ++nt)
            bf[ks * 2 + nt] = bpbase[((c * 4 + ks) * 16 + nt) * 64];
    const _Float16* xp = xbase + (size_t)c * XS_;
    #pragma unroll
    for (int mt = 0; mt < 2; ++mt)
        #pragma unroll
        for (int ks = 0; ks < 4; ++ks)
            ar[mt * 4 + ks] = *(const f16x8u*)(xp + mt * 32 + ks * 16);
}

// 16 MFMAs for channel c: scale A-frags by per-window inv-norm, accumulate
__device__ __forceinline__ void comp_c(
    const f16x8 (&bf)[8], const f16x8 (&ar)[8], const float (&iv)[2],
    f32x16 (&acc)[2][2])
{
    const _Float16 h0 = (_Float16)iv[0], h1 = (_Float16)iv[1];
    f16x8 is0, is1;
    #pragma unroll
    for (int j = 0; j < 8; ++j) { is0[j] = h0; is1[j] = h1; }
    #pragma unroll
    for (int ks = 0; ks < 4; ++ks) {
        f16x8 a0 = ar[0 * 4 + ks] * is0;          // v_pk_mul_f16 x4
        f16x8 a1 = ar[1 * 4 + ks] * is1;
        #pragma unroll
        for (int nt = 0; nt < 2; ++nt) {
            acc[0][nt] = __builtin_amdgcn_mfma_f32_32x32x16_f16(
                a0, bf[ks * 2 + nt], acc[0][nt], 0, 0, 0);
            acc[1][nt] = __builtin_amdgcn_mfma_f32_32x32x16_f16(
                a1, bf[ks * 2 + nt], acc[1][nt], 0, 0, 0);
        }
    }
}

// ---- main: register double-buffered, software-pipelined MFMA GEMM ----
// grid (16 wt, 4 ng, 32 b) = 2048 blocks, 4 waves (mg x nw = 2x2).
// Wave: 64 windows (2x32) x 64 cols (2x32); acc = 4 x f32x16 = 64 AGPR.
// Pair-peeled c-loop: loads for c+1 issue BEFORE c's MFMA block -> L2
// latency hides under >=512cy of MFMA issue. Named A/B buffer sets keep
// all register indexing compile-time (no scratch).
__global__ __launch_bounds__(256, 2)
void mcs_k(const _Float16* __restrict__ xh0, const _Float16* __restrict__ xh1,
           const _Float16* __restrict__ Bp, const float* __restrict__ invn,
           float* __restrict__ out) {
    const int wt  = blockIdx.x;
    const int ng  = blockIdx.y;           // 0..3, 128-q panel
    const int b   = blockIdx.z;
    const int tid = threadIdx.x;
    const int lane = tid & 63;
    const int wv   = tid >> 6;
    const int mg   = wv >> 1;             // window subgroup
    const int nw   = wv & 1;              // q half of panel

    const int l31 = lane & 31;
    const int lh  = lane >> 5;
    const int Wb  = wt * 128 + mg * 64;   // wave's window base
    const int m0  = Wb + l31;
    const int m1  = Wb + 32 + l31;

    // parity-selected x base keeps every f16x8 load 4B-aligned
    const _Float16* xb = (l31 & 1) ? (xh1 - 1) : xh0;
    const _Float16* xbase = xb + (size_t)b * C_ * XS_ + Wb + l31 + lh * 8;
    const float*   ivbase = invn + (size_t)b * C_ * L_;
    const f16x8*   bpbase = (const f16x8*)Bp + (ng * 4 + nw * 2) * 64 + lane;

    f32x16 acc[2][2];
    #pragma unroll
    for (int mt = 0; mt < 2; ++mt)
        #pragma unroll
        for (int nt = 0; nt < 2; ++nt)
            #pragma unroll
            for (int r = 0; r < 16; ++r) acc[mt][nt][r] = 0.f;

    f16x8 bA[8], aA[8], bB[8], aB[8];
    float ivA[2], ivB[2];

    load_c(0, bpbase, xbase, ivbase, m0, m1, bA, aA, ivA);
    #pragma unroll 1
    for (int cp = 0; cp < 4; ++cp) {
        const int c0 = cp * 2;
        load_c(c0 + 1, bpbase, xbase, ivbase, m0, m1, bB, aB, ivB);
        comp_c(bA, aA, ivA, acc);
        if (cp < 3)
            load_c(c0 + 2, bpbase, xbase, ivbase, m0, m1, bA, aA, ivA);
        comp_c(bB, aB, ivB, acc);
    }

    // epilogue: relu + max over windows. C/D: col(q) = lane&31, rows = windows;
    // reduce rows per lane, fold lane^32, then cross-wave (mg) max via LDS to
    // halve the atomic count.
    float m[2];
    #pragma unroll
    for (int nt = 0; nt < 2; ++nt) {
        float v = 0.f;
        #pragma unroll
        for (int mt = 0; mt < 2; ++mt)
            #pragma unroll
            for (int r = 0; r < 16; ++r) v = fmaxf(v, acc[mt][nt][r]);
        v = fmaxf(v, __shfl_xor(v, 32));
        m[nt] = v;
    }

    __shared__ float red[2][2][32];       // [nw][nt][l31]
    if (mg == 0 && lane < 32) {
        red[nw][0][l31] = m[0];
        red[nw][1][l31] = m[1];
    }
    __syncthreads();
    if (mg == 1 && lane < 32) {
        #pragma unroll
        for (int nt = 0; nt < 2; ++nt) {
            float v = fmaxf(m[nt], red[nw][nt][l31]);
            atomicMax((unsigned int*)(out + (size_t)b * K_ + ng * 128 + nw * 64 + nt * 32 + l31),
                      __float_as_uint(v));   // values >= 0, uint-max valid
        }
    }
}

extern "C" void kernel_launch(void* const* d_in, const int* in_sizes, int n_in,
                              void* d_out, int out_size, void* d_ws, size_t ws_size,
                              hipStream_t stream) {
    const float* x  = (const float*)d_in[0];   // (32, 8, 2048) fp32
    const float* sh = (const float*)d_in[1];   // (8, 512, 64) fp32
    float* out = (float*)d_out;                // (32, 1, 512) fp32

    // workspace: Bp 512KB | invn 2MB | xh0 ~1.06MB | xh1 ~1.06MB
    _Float16* Bp   = (_Float16*)d_ws;
    float*    invn = (float*)((char*)d_ws + (512 << 10));
    _Float16* xh0  = (_Float16*)((char*)d_ws + (512 << 10) + (2 << 20));
    _Float16* xh1  = xh0 + (size_t)B_ * C_ * XS_;

    prep_k<<<dim3(384), dim3(256), 0, stream>>>(x, sh, Bp, invn, xh0, xh1, out);
    mcs_k<<<dim3(16, 4, B_), dim3(256), 0, stream>>>(xh0, xh1, Bp, invn, out);
}

// Round 4
// 99.503 us; speedup vs baseline: 1.2944x; 1.0452x over previous
//
#include <hip/hip_runtime.h>

// B=32, C=8, L=2048, K=512, S=64, W=1985
// out[b,0,q] = max(0, max_w sum_c dot(xw_n[b,c,w,:], sn_n[c,q,:]) / 8)
//
// v5: v4 showed the wall is per-CU vector-memory feed (144 VMEM instr/CU per
// c-round vs 1024cy MFMA demand; B-panel streams from L2 every iter). Fix:
// stage the block's 16KB B-panel per c into LDS ONCE via global_load_lds
// (width 16, Bp's unit layout is exactly wave-uniform-base + lane*16),
// double-buffered, 2-phase schedule: STAGE(c+1) -> ds_read(c) -> MFMA ->
// barrier. B feed moves to the idle 128B/cyc LDS pipe; per-wave global VMEM
// drops 18 -> 10 instrs/c. A-frags stay in named double-buffered registers.

#define B_ 32
#define C_ 8
#define L_ 2048
#define K_ 512
#define S_ 64
#define W_ 1985
#define XS_ 2176                      // padded f16 row stride (L_ + 128)

typedef _Float16 f16x8  __attribute__((ext_vector_type(8)));
typedef _Float16 f16x8u __attribute__((ext_vector_type(8), aligned(4)));
typedef float    f32x16 __attribute__((ext_vector_type(16)));

// ---- prologue (unchanged, harness-verified) ----
__global__ __launch_bounds__(256)
void prep_k(const float* __restrict__ x, const float* __restrict__ sh,
            _Float16* __restrict__ Bp, float* __restrict__ invn,
            _Float16* __restrict__ xh0, _Float16* __restrict__ xh1,
            float* __restrict__ out) {
    __shared__ float xr[L_];
    const int tid = threadIdx.x;
    const int blk = blockIdx.x;

    if (blk < 128) {
        const int sb   = blk * 4 + (tid >> 6);   // 0..511 = c(8) x kq(4) x nt(16)
        const int c    = sb >> 6;
        const int kq   = (sb >> 4) & 3;
        const int nt   = sb & 15;
        const int lane = tid & 63;
        const int half = lane >> 5;
        const int q    = nt * 32 + (lane & 31);

        const float4* sp = (const float4*)(sh + (size_t)(c * K_ + q) * S_);
        float ss = 0.f;
        #pragma unroll
        for (int i = 0; i < 8; ++i) {
            float4 v = sp[half * 8 + i];
            ss += v.x * v.x + v.y * v.y + v.z * v.z + v.w * v.w;
        }
        ss += __shfl_xor(ss, 32);
        float inv = 1.f / fmaxf(sqrtf(ss), 1e-8f);

        float4 u0 = sp[kq * 4 + half * 2];
        float4 u1 = sp[kq * 4 + half * 2 + 1];
        f16x8 o;
        o[0] = (_Float16)(u0.x * inv); o[1] = (_Float16)(u0.y * inv);
        o[2] = (_Float16)(u0.z * inv); o[3] = (_Float16)(u0.w * inv);
        o[4] = (_Float16)(u1.x * inv); o[5] = (_Float16)(u1.y * inv);
        o[6] = (_Float16)(u1.z * inv); o[7] = (_Float16)(u1.w * inv);
        ((f16x8*)Bp)[((c * 4 + kq) * 16 + nt) * 64 + lane] = o;
    } else {
        const int r = blk - 128;                 // 0..255 = b*8+c
        const float* xp = x + (size_t)r * L_;
        for (int i = tid; i < L_ / 4; i += 256)
            ((float4*)xr)[i] = ((const float4*)xp)[i];
        __syncthreads();

        float* ivp = invn + (size_t)r * L_;
        const int w0 = tid * 8;
        float ss = 0.f;
        if (w0 < W_) {
            #pragma unroll
            for (int j = 0; j < S_; ++j) { float v = xr[w0 + j]; ss += v * v; }
        }
        #pragma unroll
        for (int u = 0; u < 8; ++u) {
            int w = w0 + u;
            float o = 0.f;
            if (u > 0 && w < W_)
                ss += xr[w + 63] * xr[w + 63] - xr[w - 1] * xr[w - 1];
            if (w < W_) o = 0.125f / fmaxf(sqrtf(ss), 1e-8f);
            if (w < L_) ivp[w] = o;
        }

        _Float16* p0 = xh0 + (size_t)r * XS_;
        _Float16* p1 = xh1 + (size_t)r * XS_;
        for (int i = tid; i < XS_ / 8; i += 256) {
            f16x8 o0, o1;
            #pragma unroll
            for (int j = 0; j < 8; ++j) {
                int e = i * 8 + j;
                o0[j] = (_Float16)((e     < L_) ? xr[e]     : 0.f);
                o1[j] = (_Float16)((e + 1 < L_) ? xr[e + 1] : 0.f);
            }
            ((f16x8*)p0)[i] = o0;
            ((f16x8*)p1)[i] = o1;
        }
        if (r < 64) out[r * 256 + tid] = 0.f;    // zero output
    }
}

// global -> LDS direct copy, 16B per lane (dest = uniform base + lane*16)
__device__ __forceinline__ void glds16(const void* g, void* l) {
    __builtin_amdgcn_global_load_lds(
        (const __attribute__((address_space(1))) unsigned int*)g,
        (__attribute__((address_space(3))) unsigned int*)l, 16, 0, 0);
}

// A fragments + inv-norms for channel c into NAMED register buffers
__device__ __forceinline__ void loadA(
    int c, const _Float16* __restrict__ xbase, const float* __restrict__ ivbase,
    int m0, int m1, f16x8 (&ar)[8], float (&iv)[2])
{
    iv[0] = ivbase[(size_t)c * L_ + m0];         // 0 for invalid windows
    iv[1] = ivbase[(size_t)c * L_ + m1];
    const _Float16* xp = xbase + (size_t)c * XS_;
    #pragma unroll
    for (int mt = 0; mt < 2; ++mt)
        #pragma unroll
        for (int ks = 0; ks < 4; ++ks)
            ar[mt * 4 + ks] = *(const f16x8u*)(xp + mt * 32 + ks * 16);
}

// 8 ds_read_b128 (B panel from LDS) + scale A + 16 MFMAs
__device__ __forceinline__ void compC(
    const f16x8* __restrict__ bsl, int lane, int nw,
    const f16x8 (&ar)[8], const float (&iv)[2], f32x16 (&acc)[2][2])
{
    f16x8 bf[8];
    #pragma unroll
    for (int ks = 0; ks < 4; ++ks)
        #pragma unroll
        for (int nt = 0; nt < 2; ++nt)
            bf[ks * 2 + nt] = bsl[(ks * 4 + nw * 2 + nt) * 64 + lane];

    const _Float16 h0 = (_Float16)iv[0], h1 = (_Float16)iv[1];
    f16x8 is0, is1;
    #pragma unroll
    for (int j = 0; j < 8; ++j) { is0[j] = h0; is1[j] = h1; }

    #pragma unroll
    for (int ks = 0; ks < 4; ++ks) {
        f16x8 a0 = ar[0 * 4 + ks] * is0;          // v_pk_mul_f16 x4
        f16x8 a1 = ar[1 * 4 + ks] * is1;
        #pragma unroll
        for (int nt = 0; nt < 2; ++nt) {
            acc[0][nt] = __builtin_amdgcn_mfma_f32_32x32x16_f16(
                a0, bf[ks * 2 + nt], acc[0][nt], 0, 0, 0);
            acc[1][nt] = __builtin_amdgcn_mfma_f32_32x32x16_f16(
                a1, bf[ks * 2 + nt], acc[1][nt], 0, 0, 0);
        }
    }
}

// ---- main: LDS-staged B (2-phase double buffer) + reg-pipelined A ----
// grid (16 wt, 4 ng, 32 b) = 2048 blocks, 4 waves (mg x nw = 2x2).
// Wave: 64 windows (2x32) x 64 q (2x32); acc = 4 x f32x16 = 64 AGPR.
// Per c: block stages its 16KB B-panel (ks(4) x nt(4) x 1KB units) with 16
// global_load_lds spread 4-per-wave (wave wv stages ks=wv); each wave then
// ds_reads its 8 frags. __syncthreads() between phases drains the staging.
__global__ __launch_bounds__(256, 2)
void mcs_k(const _Float16* __restrict__ xh0, const _Float16* __restrict__ xh1,
           const _Float16* __restrict__ Bp, const float* __restrict__ invn,
           float* __restrict__ out) {
    const int wt  = blockIdx.x;
    const int ng  = blockIdx.y;           // 0..3, 128-q panel
    const int b   = blockIdx.z;
    const int tid = threadIdx.x;
    const int lane = tid & 63;
    const int wv   = tid >> 6;
    const int mg   = wv >> 1;             // window subgroup
    const int nw   = wv & 1;              // q half of panel

    const int l31 = lane & 31;
    const int lh  = lane >> 5;
    const int Wb  = wt * 128 + mg * 64;   // wave's window base
    const int m0  = Wb + l31;
    const int m1  = Wb + 32 + l31;

    __shared__ f16x8 Bs[2][16][64];       // 2 x 16KB B-panel buffers
    __shared__ float red[2][2][32];       // cross-wave max

    // parity-selected x base keeps every f16x8 load 4B-aligned
    const _Float16* xb = (l31 & 1) ? (xh1 - 1) : xh0;
    const _Float16* xbase = xb + (size_t)b * C_ * XS_ + Wb + l31 + lh * 8;
    const float*   ivbase = invn + (size_t)b * C_ * L_;
    // staging source: wave wv covers ks=wv, units nt=0..3 of this ng panel
    const f16x8*   sg = (const f16x8*)Bp + ((wv * 16 + ng * 4) * 64) + lane;

    f32x16 acc[2][2];
    #pragma unroll
    for (int mt = 0; mt < 2; ++mt)
        #pragma unroll
        for (int nt = 0; nt < 2; ++nt)
            #pragma unroll
            for (int r = 0; r < 16; ++r) acc[mt][nt][r] = 0.f;

    f16x8 aA[8], aB[8];
    float ivA[2], ivB[2];

    // stage B-panel for channel c into buffer buf
    #define STAGE(c, buf)                                              \
        { _Pragma("unroll")                                            \
          for (int u = 0; u < 4; ++u)                                  \
              glds16(sg + ((c) * 64 + u) * 64, &Bs[buf][wv * 4 + u][0]); }

    STAGE(0, 0);
    loadA(0, xbase, ivbase, m0, m1, aA, ivA);
    __syncthreads();                       // buf0 ready

    #pragma unroll 1
    for (int cp = 0; cp < 4; ++cp) {
        const int c0 = cp * 2;
        STAGE(c0 + 1, 1);
        loadA(c0 + 1, xbase, ivbase, m0, m1, aB, ivB);
        compC(&Bs[0][0][0], lane, nw, aA, ivA, acc);
        __syncthreads();                   // buf1 ready, buf0 free
        if (cp < 3) {
            STAGE(c0 + 2, 0);
            loadA(c0 + 2, xbase, ivbase, m0, m1, aA, ivA);
        }
        compC(&Bs[1][0][0], lane, nw, aB, ivB, acc);
        __syncthreads();                   // buf0 ready, buf1 free
    }
    #undef STAGE

    // epilogue: relu + max over windows. C/D: col(q) = lane&31, rows = windows;
    // reduce rows per lane, fold lane^32, cross-wave (mg) max via LDS.
    float m[2];
    #pragma unroll
    for (int nt = 0; nt < 2; ++nt) {
        float v = 0.f;
        #pragma unroll
        for (int mt = 0; mt < 2; ++mt)
            #pragma unroll
            for (int r = 0; r < 16; ++r) v = fmaxf(v, acc[mt][nt][r]);
        v = fmaxf(v, __shfl_xor(v, 32));
        m[nt] = v;
    }

    if (mg == 0 && lane < 32) {
        red[nw][0][l31] = m[0];
        red[nw][1][l31] = m[1];
    }
    __syncthreads();
    if (mg == 1 && lane < 32) {
        #pragma unroll
        for (int nt = 0; nt < 2; ++nt) {
            float v = fmaxf(m[nt], red[nw][nt][l31]);
            atomicMax((unsigned int*)(out + (size_t)b * K_ + ng * 128 + nw * 64 + nt * 32 + l31),
                      __float_as_uint(v));   // values >= 0, uint-max valid
        }
    }
}

extern "C" void kernel_launch(void* const* d_in, const int* in_sizes, int n_in,
                              void* d_out, int out_size, void* d_ws, size_t ws_size,
                              hipStream_t stream) {
    const float* x  = (const float*)d_in[0];   // (32, 8, 2048) fp32
    const float* sh = (const float*)d_in[1];   // (8, 512, 64) fp32
    float* out = (float*)d_out;                // (32, 1, 512) fp32

    // workspace: Bp 512KB | invn 2MB | xh0 ~1.06MB | xh1 ~1.06MB
    _Float16* Bp   = (_Float16*)d_ws;
    float*    invn = (float*)((char*)d_ws + (512 << 10));
    _Float16* xh0  = (_Float16*)((char*)d_ws + (512 << 10) + (2 << 20));
    _Float16* xh1  = xh0 + (size_t)B_ * C_ * XS_;

    prep_k<<<dim3(384), dim3(256), 0, stream>>>(x, sh, Bp, invn, xh0, xh1, out);
    mcs_k<<<dim3(16, 4, B_), dim3(256), 0, stream>>>(xh0, xh1, Bp, invn, out);
}